// Round 5
// baseline (216.247 us; speedup 1.0000x reference)
//
#include <hip/hip_runtime.h>
#include <cmath>

#define N_NODES 30460
#define D 64
#define B 128
#define K_SEL 6924
#define S_TOT (B * K_SEL)      /* 886272 */
#define NPAD 30464             /* 30461 rounded up to x64; pad rows never read */

// ws layout (floats): port [B*D] | tw [2*B] | U [B*NPAD] | P [B*NPAD]  (~31.2 MB)
#define WS_PORT 0
#define WS_TW   (B * D)
#define WS_TABU (B * D + 2 * B)
#define WS_TABP (WS_TABU + B * NPAD)

// ---- k1: portrait (blocks 0..31) + U-table (blocks 32..983) ----
__global__ __launch_bounds__(256) void k1_port_u(
    const float* __restrict__ graph, const float* __restrict__ abs_e,
    const float* __restrict__ utter,
    const float* __restrict__ Wa, const float* __restrict__ Va,
    const int* __restrict__ midx, float* __restrict__ ws) {
    const int blk = blockIdx.x, tid = threadIdx.x;
    const int wave = tid >> 6, lane = tid & 63;

    if (blk < 32) {
        // ---- portrait: 4 waves x 32 blocks = 128 batches, no atomics ----
        __shared__ float sWa[D * 20];
        __shared__ float sVa[20];
        __shared__ float sExp[4][64];
        __shared__ int   sIdx[4][64];
        for (int i = tid; i < D * 20; i += 256) sWa[i] = Wa[i];
        if (tid < 20) sVa[tid] = Va[tid];
        __syncthreads();
        int b = blk * 4 + wave;
        float e = 0.f; int mi = 0;
        if (lane < 50) {
            mi = midx[b * 50 + lane];
            const float* me = graph + (size_t)mi * D;
            float h[20];
#pragma unroll
            for (int j = 0; j < 20; j++) h[j] = 0.f;
            for (int d = 0; d < D; d++) {
                float v = me[d];
#pragma unroll
                for (int j = 0; j < 20; j++) h[j] += v * sWa[d * 20 + j];
            }
            float beta = 0.f;
#pragma unroll
            for (int j = 0; j < 20; j++) beta += tanhf(h[j]) * sVa[j];
            e = expf(beta);
        }
        sExp[wave][lane] = e;
        sIdx[wave][lane] = mi;
        __syncthreads();
        float x = sExp[wave][lane];
        x += __shfl_xor(x, 32, 64); x += __shfl_xor(x, 16, 64);
        x += __shfl_xor(x, 8, 64);  x += __shfl_xor(x, 4, 64);
        x += __shfl_xor(x, 2, 64);  x += __shfl_xor(x, 1, 64);
        float acc = 0.f;
#pragma unroll 5
        for (int m = 0; m < 50; m++)
            acc += sExp[wave][m] * graph[(size_t)sIdx[wave][m] * D + lane];
        ws[WS_PORT + b * D + lane] = acc / x;
        return;
    }

    // ---- U-table: 952 units = (119 n-chunks of 256) x (8 b-chunks of 16) ----
    int t = blk - 32;
    int nbk = t >> 3, bc = t & 7;
    int n = nbk * 256 + tid;
    if (n > N_NODES) return;
    const float4* grow = (const float4*)((n < N_NODES) ? (graph + (size_t)n * D) : abs_e);
    float4 g4[16];
#pragma unroll
    for (int k = 0; k < 16; k++) g4[k] = grow[k];
    float* tabU = ws + WS_TABU;
    int b0 = bc * 16;
    for (int b = b0; b < b0 + 16; ++b) {
        const float* ub = utter + (size_t)b * D;
        float du = 0.f;
#pragma unroll
        for (int k = 0; k < 16; k++) {
            float4 gv = g4[k];
            du += gv.x * ub[4*k] + gv.y * ub[4*k+1] + gv.z * ub[4*k+2] + gv.w * ub[4*k+3];
        }
        tabU[(size_t)b * NPAD + n] = du;
    }
}

// ---- k2: tw (blocks 0..63, one wave per (layer,group)) + P-table (64..1015) ----
__global__ __launch_bounds__(256) void k2_p_tw(
    const float* __restrict__ graph, const float* __restrict__ abs_e,
    const float* __restrict__ utter,
    const float* __restrict__ W1w, const float* __restrict__ W1b,
    const float* __restrict__ W2w, const float* __restrict__ W2b,
    const int* __restrict__ gb0, const int* __restrict__ la0, const int* __restrict__ it0,
    const int* __restrict__ gb1, const int* __restrict__ la1, const int* __restrict__ it1,
    float* __restrict__ ws) {
    const int blk = blockIdx.x, tid = threadIdx.x;
    const int wave = tid >> 6, lane = tid & 63;
    const float* port = ws + WS_PORT;

    if (blk < 64) {
        int lg = blk * 4 + wave;               // 0..255
        int l = lg >> 7, g = lg & (B - 1);
        const int* gbp = l ? gb1 : gb0;
        const int* lap = l ? la1 : la0;
        const int* itp = l ? it1 : it0;
        const float* Ww = l ? W2w : W1w;
        const float* Wb = l ? W2b : W1b;
        int gb = gbp[g], li = lap[g], it = itp[g];
        const float* wr = Ww + it * 3 * D;
        float uv = utter[(size_t)gb * D + lane];
        float pv = port[(size_t)gb * D + lane];
        float sv = (li < N_NODES) ? graph[(size_t)li * D + lane] : abs_e[lane];
        float a = wr[lane] * uv + wr[D + lane] * pv + wr[2 * D + lane] * sv;
        a += __shfl_xor(a, 32, 64); a += __shfl_xor(a, 16, 64);
        a += __shfl_xor(a, 8, 64);  a += __shfl_xor(a, 4, 64);
        a += __shfl_xor(a, 2, 64);  a += __shfl_xor(a, 1, 64);
        if (lane == 0) ws[WS_TW + l * B + g] = 1.f / (1.f + expf(-(a + Wb[it])));
        return;
    }

    int t = blk - 64;
    int nbk = t >> 3, bc = t & 7;
    int n = nbk * 256 + tid;
    if (n > N_NODES) return;
    const float4* grow = (const float4*)((n < N_NODES) ? (graph + (size_t)n * D) : abs_e);
    float4 g4[16];
#pragma unroll
    for (int k = 0; k < 16; k++) g4[k] = grow[k];
    float* tabP = ws + WS_TABP;
    int b0 = bc * 16;
    for (int b = b0; b < b0 + 16; ++b) {
        const float* pb = port + (size_t)b * D;
        float dp = 0.f;
#pragma unroll
        for (int k = 0; k < 16; k++) {
            float4 gv = g4[k];
            dp += gv.x * pb[4*k] + gv.y * pb[4*k+1] + gv.z * pb[4*k+2] + gv.w * pb[4*k+3];
        }
        tabP[(size_t)b * NPAD + n] = dp;
    }
}

// ---- k3: scoring — two 4B gathers + 1 FMA per output ----
__global__ __launch_bounds__(256) void k_out(
    const int* __restrict__ si0, const int* __restrict__ si1,
    const float* __restrict__ ws, float* __restrict__ out) {
    const float* tws  = ws + WS_TW;
    const float* tabU = ws + WS_TABU;
    const float* tabP = ws + WS_TABP;
    int layer = blockIdx.y;
    const int* __restrict__ si = layer ? si1 : si0;
    int s = blockIdx.x * 256 + threadIdx.x;
    int idx = si[s];
    unsigned bat = (unsigned)s / (unsigned)K_SEL;   // sel_batch/group_index = repeat(arange(B),K)
    float tw = tws[layer * B + bat];
    size_t o = (size_t)bat * NPAD + idx;
    float u = tabU[o], p = tabP[o];
    __builtin_nontemporal_store(p + tw * (u - p), &out[(size_t)layer * S_TOT + s]);
}

extern "C" void kernel_launch(void* const* d_in, const int* in_sizes, int n_in,
                              void* d_out, int out_size, void* d_ws, size_t ws_size,
                              hipStream_t stream) {
    const float* graph = (const float*)d_in[0];
    const float* utter = (const float*)d_in[1];
    const float* abs_e = (const float*)d_in[2];
    const float* Wa    = (const float*)d_in[3];
    const float* Va    = (const float*)d_in[4];
    const float* W1w   = (const float*)d_in[5];
    const float* W1b   = (const float*)d_in[6];
    const float* W2w   = (const float*)d_in[7];
    const float* W2b   = (const float*)d_in[8];
    const int* midx = (const int*)d_in[9];
    const int* si0 = (const int*)d_in[11];
    const int* gb0 = (const int*)d_in[14];
    const int* la0 = (const int*)d_in[15];
    const int* it0 = (const int*)d_in[16];
    const int* si1 = (const int*)d_in[17];
    const int* gb1 = (const int*)d_in[20];
    const int* la1 = (const int*)d_in[21];
    const int* it1 = (const int*)d_in[22];

    float* ws = (float*)d_ws;

    k1_port_u<<<32 + 952, 256, 0, stream>>>(graph, abs_e, utter, Wa, Va, midx, ws);

    k2_p_tw<<<64 + 952, 256, 0, stream>>>(graph, abs_e, utter,
                                          W1w, W1b, W2w, W2b,
                                          gb0, la0, it0, gb1, la1, it1, ws);

    dim3 grid(S_TOT / 256, 2);   // 3462 x 2
    k_out<<<grid, 256, 0, stream>>>(si0, si1, ws, (float*)d_out);
}

// Round 6
// 169.651 us; speedup vs baseline: 1.2747x; 1.2747x over previous
//
#include <hip/hip_runtime.h>
#include <cmath>

#define N_NODES 30460
#define D 64
#define B 128
#define K_SEL 6924
#define S_TOT (B * K_SEL)      /* 886272 */
#define NPAD 30464             /* 238 * 128 ; pad rows never gathered */
#define NB_CHUNKS 238          /* rows per chunk = 128 */

// ws layout (floats): port [B*D] | tw [2*B] | tab float2 [B*NPAD]  (~31.3 MB)
#define WS_PORT 0
#define WS_TW   (B * D)
#define WS_TAB  (B * D + 2 * B)

// ---- portrait: 4 waves/block x 32 blocks = 128 batches; no atomics ----
__global__ __launch_bounds__(256) void k_port(
    const float* __restrict__ graph, const float* __restrict__ Wa,
    const float* __restrict__ Va, const int* __restrict__ midx,
    float* __restrict__ ws) {
    __shared__ float sWa[D * 20];
    __shared__ float sVa[20];
    __shared__ float sExp[4][64];
    __shared__ int   sIdx[4][64];
    int tid = threadIdx.x, wave = tid >> 6, lane = tid & 63;
    for (int i = tid; i < D * 20; i += 256) sWa[i] = Wa[i];
    if (tid < 20) sVa[tid] = Va[tid];
    __syncthreads();
    int b = blockIdx.x * 4 + wave;
    float e = 0.f; int mi = 0;
    if (lane < 50) {
        mi = midx[b * 50 + lane];
        const float* me = graph + (size_t)mi * D;
        float h[20];
#pragma unroll
        for (int j = 0; j < 20; j++) h[j] = 0.f;
        for (int d = 0; d < D; d++) {
            float v = me[d];
#pragma unroll
            for (int j = 0; j < 20; j++) h[j] += v * sWa[d * 20 + j];
        }
        float beta = 0.f;
#pragma unroll
        for (int j = 0; j < 20; j++) beta += tanhf(h[j]) * sVa[j];
        e = expf(beta);
    }
    sExp[wave][lane] = e;
    sIdx[wave][lane] = mi;
    __syncthreads();
    float x = sExp[wave][lane];
    x += __shfl_xor(x, 32, 64); x += __shfl_xor(x, 16, 64);
    x += __shfl_xor(x, 8, 64);  x += __shfl_xor(x, 4, 64);
    x += __shfl_xor(x, 2, 64);  x += __shfl_xor(x, 1, 64);
    float acc = 0.f;
#pragma unroll 5
    for (int m = 0; m < 50; m++)
        acc += sExp[wave][m] * graph[(size_t)sIdx[wave][m] * D + lane];
    ws[WS_PORT + b * D + lane] = acc / x;
}

// ---- table GEMM: tab[b][n] = (utter[b].G[n], port[b].G[n]) ; + tw side-task ----
// blocks 0..63: tw (one wave per (layer,group)); blocks 64..1015: 238 nb x 4 cb
__global__ __launch_bounds__(256) void k_table(
    const float* __restrict__ graph, const float* __restrict__ abs_e,
    const float* __restrict__ utter,
    const float* __restrict__ W1w, const float* __restrict__ W1b,
    const float* __restrict__ W2w, const float* __restrict__ W2b,
    const int* __restrict__ gb0, const int* __restrict__ la0, const int* __restrict__ it0,
    const int* __restrict__ gb1, const int* __restrict__ la1, const int* __restrict__ it1,
    float* __restrict__ ws) {
    const int blk = blockIdx.x, t = threadIdx.x;
    const float* port = ws + WS_PORT;

    __shared__ float Gs[128 * 68];   // 128 graph rows, stride 68 (bank-spread, 16B-aligned)
    __shared__ float Xs[64 * 68];    // 64 X rows: xl = 2*b_local + (0:utter,1:port)

    if (blk < 64) {
        int wave = t >> 6, lane = t & 63;
        int lg = blk * 4 + wave;               // 0..255
        int l = lg >> 7, g = lg & (B - 1);
        const int* gbp = l ? gb1 : gb0;
        const int* lap = l ? la1 : la0;
        const int* itp = l ? it1 : it0;
        const float* Ww = l ? W2w : W1w;
        const float* Wb = l ? W2b : W1b;
        int gb = gbp[g], li = lap[g], it = itp[g];
        const float* wr = Ww + it * 3 * D;
        float uv = utter[(size_t)gb * D + lane];
        float pv = port[(size_t)gb * D + lane];
        float sv = (li < N_NODES) ? graph[(size_t)li * D + lane] : abs_e[lane];
        float a = wr[lane] * uv + wr[D + lane] * pv + wr[2 * D + lane] * sv;
        a += __shfl_xor(a, 32, 64); a += __shfl_xor(a, 16, 64);
        a += __shfl_xor(a, 8, 64);  a += __shfl_xor(a, 4, 64);
        a += __shfl_xor(a, 2, 64);  a += __shfl_xor(a, 1, 64);
        if (lane == 0) ws[WS_TW + l * B + g] = 1.f / (1.f + expf(-(a + Wb[it])));
        return;
    }

    int tb = blk - 64;
    int nb = tb >> 2, cb = tb & 3;    // nb: 0..237, cb: 0..3 (32 batches each)

    // ---- stage G: 128 rows x 256 B, fully coalesced (1 KiB per instr) ----
#pragma unroll
    for (int p = 0; p < 8; ++p) {
        int f4 = p * 256 + t;
        int row = f4 >> 4, c4 = f4 & 15;
        int n = nb * 128 + row;
        const float* src = (n < N_NODES) ? (graph + (size_t)n * D) : abs_e;
        *(float4*)&Gs[row * 68 + c4 * 4] = *(const float4*)(src + c4 * 4);
    }
    // ---- stage X: 64 rows (32 batches x {utter,port}) ----
#pragma unroll
    for (int p = 0; p < 4; ++p) {
        int f4 = p * 256 + t;
        int xl = f4 >> 4, c4 = f4 & 15;
        int b = cb * 32 + (xl >> 1);
        const float* src = (xl & 1) ? (port + (size_t)b * D) : (utter + (size_t)b * D);
        *(float4*)&Xs[xl * 68 + c4 * 4] = *(const float4*)(src + c4 * 4);
    }
    __syncthreads();

    // ---- compute: thread tile 8 rows x 4 cols (2 batches x {U,P}) ----
    int tn = t & 15, tcg = t >> 4;
    float acc[8][4];
#pragma unroll
    for (int i = 0; i < 8; ++i)
#pragma unroll
        for (int j = 0; j < 4; ++j) acc[i][j] = 0.f;

#pragma unroll 4
    for (int dq = 0; dq < 16; ++dq) {
        float4 gf[8], xf[4];
#pragma unroll
        for (int i = 0; i < 8; ++i)
            gf[i] = *(float4*)&Gs[(tn + 16 * i) * 68 + dq * 4];
#pragma unroll
        for (int j = 0; j < 4; ++j) {
            int xl = 2 * (tcg + 16 * (j >> 1)) + (j & 1);
            xf[j] = *(float4*)&Xs[xl * 68 + dq * 4];
        }
#pragma unroll
        for (int i = 0; i < 8; ++i)
#pragma unroll
            for (int j = 0; j < 4; ++j)
                acc[i][j] += gf[i].x * xf[j].x + gf[i].y * xf[j].y
                           + gf[i].z * xf[j].z + gf[i].w * xf[j].w;
    }

    // ---- store float2 (U,P); 128B-contiguous per 16-lane group ----
    float2* tab = (float2*)(ws + WS_TAB);
#pragma unroll
    for (int jj = 0; jj < 2; ++jj) {
        int b = cb * 32 + tcg + 16 * jj;
#pragma unroll
        for (int i = 0; i < 8; ++i) {
            int n = nb * 128 + tn + 16 * i;
            tab[(size_t)b * NPAD + n] = make_float2(acc[i][jj * 2], acc[i][jj * 2 + 1]);
        }
    }
}

// ---- scoring: one 8B gather + 1 FMA per output ----
__global__ __launch_bounds__(256) void k_out(
    const int* __restrict__ si0, const int* __restrict__ si1,
    const float* __restrict__ ws, float* __restrict__ out) {
    const float* tws = ws + WS_TW;
    const float2* tab = (const float2*)(ws + WS_TAB);
    int layer = blockIdx.y;
    const int* __restrict__ si = layer ? si1 : si0;
    int s = blockIdx.x * 256 + threadIdx.x;
    int idx = si[s];
    unsigned bat = (unsigned)s / (unsigned)K_SEL;   // repeat(arange(B), K)
    float tw = tws[layer * B + bat];
    float2 v = tab[(size_t)bat * NPAD + idx];
    __builtin_nontemporal_store(v.y + tw * (v.x - v.y), &out[(size_t)layer * S_TOT + s]);
}

extern "C" void kernel_launch(void* const* d_in, const int* in_sizes, int n_in,
                              void* d_out, int out_size, void* d_ws, size_t ws_size,
                              hipStream_t stream) {
    const float* graph = (const float*)d_in[0];
    const float* utter = (const float*)d_in[1];
    const float* abs_e = (const float*)d_in[2];
    const float* Wa    = (const float*)d_in[3];
    const float* Va    = (const float*)d_in[4];
    const float* W1w   = (const float*)d_in[5];
    const float* W1b   = (const float*)d_in[6];
    const float* W2w   = (const float*)d_in[7];
    const float* W2b   = (const float*)d_in[8];
    const int* midx = (const int*)d_in[9];
    const int* si0 = (const int*)d_in[11];
    const int* gb0 = (const int*)d_in[14];
    const int* la0 = (const int*)d_in[15];
    const int* it0 = (const int*)d_in[16];
    const int* si1 = (const int*)d_in[17];
    const int* gb1 = (const int*)d_in[20];
    const int* la1 = (const int*)d_in[21];
    const int* it1 = (const int*)d_in[22];

    float* ws = (float*)d_ws;

    k_port<<<32, 256, 0, stream>>>(graph, Wa, Va, midx, ws);

    k_table<<<64 + NB_CHUNKS * 4, 256, 0, stream>>>(graph, abs_e, utter,
                                                    W1w, W1b, W2w, W2b,
                                                    gb0, la0, it0, gb1, la1, it1, ws);

    dim3 grid(S_TOT / 256, 2);   // 3462 x 2
    k_out<<<grid, 256, 0, stream>>>(si0, si1, ws, (float*)d_out);
}